// Round 1
// baseline (92.241 us; speedup 1.0000x reference)
//
#include <hip/hip_runtime.h>

// ws layout:
//   [0..40)    5 doubles: sumA, sumA2, sumN, sumN2, reluSum
//   [64..72)   2 ints: pcnt, ncnt
//   [256..)    float posA[N]  (compacted a_i = 1 - p_i for positives)
#define ACC_SUMA   0
#define ACC_SUMA2  1
#define ACC_SUMN   2
#define ACC_SUMN2  3
#define ACC_RELU   4

__device__ __forceinline__ float wave_reduce_f32(float v) {
    #pragma unroll
    for (int off = 32; off > 0; off >>= 1) v += __shfl_xor(v, off, 64);
    return v;
}

__device__ __forceinline__ double wave_reduce_f64(double v) {
    #pragma unroll
    for (int off = 32; off > 0; off >>= 1) v += __shfl_xor(v, off, 64);
    return v;
}

// Kernel A: one pass over N. Computes moments for the squared-term
// decomposition and compacts positive a_i = 1 - p_i into posA.
__global__ void aucm_moments(const float* __restrict__ preds,
                             const int* __restrict__ tgt,
                             int n, double* __restrict__ acc,
                             int* __restrict__ cnts,
                             float* __restrict__ posA) {
    int i = blockIdx.x * blockDim.x + threadIdx.x;
    float a = 0.f, a2 = 0.f, nv = 0.f, n2 = 0.f;
    bool isPos = false, isNeg = false;
    if (i < n) {
        float p = preds[i];
        int t = tgt[i];
        if (t == 1) { isPos = true; float av = 1.0f - p; a = av; a2 = av * av; }
        else        { isNeg = true; nv = p; n2 = p * p; }
    }
    // Compact positives (compiler coalesces the ticket atomic per-wave).
    if (isPos) {
        int idx = atomicAdd(&cnts[0], 1);
        posA[idx] = a;
    }
    if (isNeg) atomicAdd(&cnts[1], 1);

    // Wave-level reduction of the four moments, then one double atomic per wave.
    float ra  = wave_reduce_f32(a);
    float ra2 = wave_reduce_f32(a2);
    float rn  = wave_reduce_f32(nv);
    float rn2 = wave_reduce_f32(n2);
    if ((threadIdx.x & 63) == 0) {
        atomicAdd(&acc[ACC_SUMA],  (double)ra);
        atomicAdd(&acc[ACC_SUMA2], (double)ra2);
        atomicAdd(&acc[ACC_SUMN],  (double)rn);
        atomicAdd(&acc[ACC_SUMN2], (double)rn2);
    }
}

// Kernel B: reluSum = sum over (i in pos, j in neg) of relu(a_i + p_j).
// Positives staged in LDS tiles (broadcast reads). Each thread owns one j.
// gridDim.y slices the positive tiles for more parallelism.
#define TS 512
__global__ void aucm_relu_pairs(const float* __restrict__ preds,
                                const int* __restrict__ tgt,
                                int n,
                                const int* __restrict__ cnts,
                                const float* __restrict__ posA,
                                double* __restrict__ acc) {
    __shared__ float tileA[TS];
    const int pcnt = cnts[0];
    const int j = blockIdx.x * blockDim.x + threadIdx.x;
    float pj = 0.f;
    bool neg = false;
    if (j < n) { pj = preds[j]; neg = (tgt[j] == 0); }

    double accd = 0.0;
    for (int t0 = blockIdx.y * TS; t0 < pcnt; t0 += gridDim.y * TS) {
        const int cnt = min(TS, pcnt - t0);
        __syncthreads();
        for (int k = threadIdx.x; k < cnt; k += blockDim.x)
            tileA[k] = posA[t0 + k];
        __syncthreads();
        if (neg) {
            float s = 0.f;
            int k = 0;
            for (; k + 3 < cnt; k += 4) {
                float d0 = tileA[k]     + pj;
                float d1 = tileA[k + 1] + pj;
                float d2 = tileA[k + 2] + pj;
                float d3 = tileA[k + 3] + pj;
                s += fmaxf(d0, 0.f) + fmaxf(d1, 0.f)
                   + fmaxf(d2, 0.f) + fmaxf(d3, 0.f);
            }
            for (; k < cnt; ++k) s += fmaxf(tileA[k] + pj, 0.f);
            accd += (double)s;
        }
    }
    double r = wave_reduce_f64(accd);
    if ((threadIdx.x & 63) == 0 && r != 0.0)
        atomicAdd(&acc[ACC_RELU], r);
}

// Kernel C: finalize.
__global__ void aucm_finalize(const double* __restrict__ acc,
                              const int* __restrict__ cnts,
                              float* __restrict__ out, float margin) {
    double sumA = acc[ACC_SUMA], sumA2 = acc[ACC_SUMA2];
    double sumN = acc[ACC_SUMN], sumN2 = acc[ACC_SUMN2];
    double relu = acc[ACC_RELU];
    double P  = (double)cnts[0];
    double Nn = (double)cnts[1];
    double sq = Nn * sumA2 + 2.0 * sumA * sumN + P * sumN2;
    double loss = (sq + (double)margin * relu) / (P * Nn);
    out[0] = (float)loss;
}

extern "C" void kernel_launch(void* const* d_in, const int* in_sizes, int n_in,
                              void* d_out, int out_size, void* d_ws, size_t ws_size,
                              hipStream_t stream) {
    const float* preds = (const float*)d_in[0];
    const int*   tgt   = (const int*)d_in[1];
    float* out = (float*)d_out;
    const int n = in_sizes[0];

    char* ws = (char*)d_ws;
    double* acc  = (double*)(ws + 0);
    int*    cnts = (int*)(ws + 64);
    float*  posA = (float*)(ws + 256);

    // Zero accumulators + counters (ws is poisoned 0xAA before every call).
    hipMemsetAsync(d_ws, 0, 256, stream);

    const int block = 256;
    const int gx = (n + block - 1) / block;   // 64 blocks for N=16384

    aucm_moments<<<gx, block, 0, stream>>>(preds, tgt, n, acc, cnts, posA);
    aucm_relu_pairs<<<dim3(gx, 4), block, 0, stream>>>(preds, tgt, n, cnts, posA, acc);
    aucm_finalize<<<1, 1, 0, stream>>>(acc, cnts, out, 1.0f /*MARGIN*/);
}